// Round 14
// baseline (83.132 us; speedup 1.0000x reference)
//
#include <hip/hip_runtime.h>
#include <hip/hip_bf16.h>

// Sizes (fixed by the reference)
#define NN 32
#define CC 64
#define TT 300
#define VV 25
#define KK 3
#define OO 64
#define TB 4          // time steps per block
#define SB (TB * VV)  // 100 output spatial positions per block
#define NREP 8        // replicated stats accumulator slots

// ws layout (floats):
//  [128..1152)     NREP*128 replica stats accumulators (sum, sumsq per channel)
//  [1152..7296)    Wpk: 1536 short8 W-fragments (24 KB)
//  [7296..8832)    Apk: 384 short8 A-fragments (6 KB)
//  [16384..)       bf16 y buffer (30.72 MB) if ws_size permits
#define REP_OFF 128
#define WPK_OFF 1152
#define APK_OFF (1152 + 6144)
#define YBF_OFF 16384
#define YBF_BYTES ((size_t)NN * OO * TT * VV * 2)
#define WS_NEED_BF16 ((size_t)YBF_OFF * 4 + YBF_BYTES)

typedef __attribute__((ext_vector_type(8))) short short8;  // 8 bf16 = 4 VGPR
typedef __attribute__((ext_vector_type(4))) float f32x4;
typedef __attribute__((ext_vector_type(4))) unsigned int u32x4;

// f32 -> bf16 RNE, integer path (cold code: prep_pack only)
__device__ __forceinline__ unsigned short f2bf(float f) {
    unsigned u = __builtin_bit_cast(unsigned, f);
    u += 0x7FFFu + ((u >> 16) & 1u);
    return (unsigned short)(u >> 16);
}
__device__ __forceinline__ float bf2f(unsigned short b) {
    return __builtin_bit_cast(float, (unsigned)b << 16);
}
// hot path: official paired convert (RNE, x -> low half); compiler emits the
// packed HW convert (m240: don't hand-write the asm — R13's asm version was
// the correctness bug). memcpy instead of bit_cast: __hip_bfloat162 is not
// trivially copyable on this ROCm.
__device__ __forceinline__ unsigned pk2(float a, float b) {
    __hip_bfloat162 h = __float22bfloat162_rn(make_float2(a, b));
    unsigned r;
    __builtin_memcpy(&r, &h, sizeof(r));
    return r;
}
__device__ __forceinline__ int xswz(int row) { return ((row >> 1) & 3) << 3; }

// One-time: zero replica stats, pack W and A into exact MFMA fragment layout.
__global__ __launch_bounds__(512) void prep_pack(const float* __restrict__ A,
                                                 const float* __restrict__ W,
                                                 float* __restrict__ ws) {
    const int i = blockIdx.x * 512 + threadIdx.x;  // grid 4 -> 2048 threads
    if (i < REP_OFF + NREP * 128) ws[i] = 0.0f;    // 1152 floats
    unsigned short* Wpk = reinterpret_cast<unsigned short*>(ws + WPK_OFF);
    unsigned short* Apk = reinterpret_cast<unsigned short*>(ws + APK_OFF);
    if (i < 1536) {
        // Wpk[mt][kap][lane]: A-operand frag, row o = mt*16+li, k-elems = kap*32+g*8+e
        int mt = i / 384, r = i - mt * 384;
        int kap = r / 64, lane = r - kap * 64;
        int li = lane & 15, g = lane >> 4;
        int o  = mt * 16 + li;
        int k  = kap >> 1, c0 = (kap & 1) * 32 + g * 8;
        const float* wp = W + ((size_t)(k * OO + o)) * CC + c0;
#pragma unroll
        for (int e = 0; e < 8; ++e) Wpk[i * 8 + e] = f2bf(wp[e]);
    } else if (i < 1920) {
        // Apk[k*2+nt][lane]: B-operand frag (A^T), col w = nt*16+li, k-elems v = g*8+e
        int j = i - 1536;
        int k = j / 128, r = j - k * 128;
        int nt = r / 64, lane = r - nt * 64;
        int li = lane & 15, g = lane >> 4;
        int w = nt * 16 + li;
#pragma unroll
        for (int e = 0; e < 8; ++e) {
            int v = g * 8 + e;
            float val = (v < VV && w < VV) ? A[(k * VV + v) * VV + w] : 0.0f;
            Apk[j * 8 + e] = f2bf(val);
        }
    }
}

// Block: (n, 4 time steps), 512 threads = 8 waves. 2-barrier schedule + fused stats.
//  Phase A: stage x -> bf16 x_s (+ stage Wpk -> LDS, overlapped)
//  Phase B: GEMM1 all k -> xa_s[s=t*25+w][kc=k*64+c]  (packed uint2 epilogue)
//  Phase C: GEMM2 K=192 from LDS Wpk -> stores + per-u-iter shfl-reduced stats
//  (stat state never spans barriers; reduction is within-phase -> no spill).
template <int BF16Y>
__global__ __launch_bounds__(512, 4) void gcn_main(const float* __restrict__ x,
                                                   float* __restrict__ ws,
                                                   float* __restrict__ ypre) {
    __shared__ alignas(16) unsigned short x_s[256 * 32];    // 16.0 KB
    __shared__ alignas(16) unsigned short xa_s[100 * 192];  // 38.4 KB (no pad rows:
                                                            // invalid srow reads clamped)
    __shared__ alignas(16) unsigned short wpk_s[1536 * 8];  // 24.0 KB
    __shared__ float stats_s[128];
    // total ~80 KB -> 2 blocks/CU

    const int bid  = blockIdx.x;
    const int n    = bid / (TT / TB);
    const int t0   = (bid % (TT / TB)) * TB;
    const int tid  = threadIdx.x;
    const int lane = tid & 63;
    const int wid  = tid >> 6;
    const int li   = lane & 15;   // fragment row/col index
    const int g    = lane >> 4;   // 16-lane group: k-elems = 8g..8g+7

    if (tid < 128) stats_s[tid] = 0.0f;

    // ---- Phase A0: stage Wpk -> LDS (3 x 16B per thread; latency hides under A)
    {
        const u32x4* Wg = reinterpret_cast<const u32x4*>(ws + WPK_OFF);
        u32x4* Wl = reinterpret_cast<u32x4*>(wpk_s);
#pragma unroll
        for (int m = 0; m < 3; ++m) Wl[tid + m * 512] = Wg[tid + m * 512];
    }

    // ---- Phase A: stage x (coalesced float4 global, paired cvt + b16 LDS writes)
    const float* xg = x + (size_t)n * (CC * TT * VV) + (size_t)t0 * VV;
    for (int idx = tid; idx < CC * 25; idx += 512) {  // 1600 float4
        int c = idx / 25, q = idx - c * 25;
        const float4 f = *reinterpret_cast<const float4*>(xg + (size_t)c * (TT * VV) + q * 4);
        unsigned u01 = pk2(f.x, f.y);
        unsigned u23 = pk2(f.z, f.w);
        unsigned short e[4] = {(unsigned short)u01, (unsigned short)(u01 >> 16),
                               (unsigned short)u23, (unsigned short)(u23 >> 16)};
        int s0 = q * 4;
#pragma unroll
        for (int i = 0; i < 4; ++i) {
            int sp = s0 + i;               // may straddle the 25-joint boundary
            int t = sp / 25, v = sp - t * 25;
            int row = t * 64 + c;
            x_s[row * 32 + (v ^ xswz(row))] = e[i];
        }
    }
    for (int idx = tid; idx < 256 * 7; idx += 512) {  // zero-fill K-pad v=25..31
        int row = idx / 7, v = 25 + (idx - row * 7);
        x_s[row * 32 + (v ^ xswz(row))] = 0;
    }

    // ---- A^T B-fragments: 6 coalesced 16B loads (pre-packed)
    short8 afrag[6];
#pragma unroll
    for (int kn = 0; kn < 6; ++kn)
        afrag[kn] = *reinterpret_cast<const short8*>(
            reinterpret_cast<const unsigned short*>(ws + APK_OFF) + ((size_t)kn * 64 + lane) * 8);

    __syncthreads();

    // ---- Phase B: GEMM1. M=(t*64+c) 256 rows = 16 Mtiles, N=w (2 tiles), K=32.
    for (int mt = wid; mt < 16; mt += 8) {
        const int row = mt * 16 + li;
        const short8 xf = *reinterpret_cast<const short8*>(
            &x_s[row * 32 + ((g * 8) ^ xswz(row))]);
        const int r0 = mt * 16 + g * 4;
        const int t = r0 >> 6, c0 = r0 & 63;
        const int s0 = t * 25 + li;
        const int w1 = 16 + li;
        const bool w1v = w1 < VV;
        const int s1 = t * 25 + w1;
        unsigned short* p0 = &xa_s[s0 * 192 + (c0 ^ ((s0 & 7) << 3))];
        unsigned short* p1 = &xa_s[(w1v ? s1 : 0) * 192 + (c0 ^ (((w1v ? s1 : 0) & 7) << 3))];
#pragma unroll
        for (int k = 0; k < KK; ++k) {
            f32x4 a0 = {0.f,0.f,0.f,0.f}, a1 = {0.f,0.f,0.f,0.f};
            a0 = __builtin_amdgcn_mfma_f32_16x16x32_bf16(xf, afrag[k * 2 + 0], a0, 0, 0, 0);
            a1 = __builtin_amdgcn_mfma_f32_16x16x32_bf16(xf, afrag[k * 2 + 1], a1, 0, 0, 0);
            uint2 q0 = make_uint2(pk2(a0[0], a0[1]), pk2(a0[2], a0[3]));
            *reinterpret_cast<uint2*>(p0 + k * 64) = q0;
            if (w1v) {
                uint2 q1 = make_uint2(pk2(a1[0], a1[1]), pk2(a1[2], a1[3]));
                *reinterpret_cast<uint2*>(p1 + k * 64) = q1;
            }
        }
    }
    __syncthreads();

    // ---- Phase C: GEMM2. M=o (4 Mtiles), N=s (7 Ntiles, last ragged), K=192 (6 MFMA).
    // W fragments from LDS; invalid srow lanes clamp the xa read to row 0 (their
    // output columns are excluded from stores and stats).
    unsigned short* ybf = reinterpret_cast<unsigned short*>(ws + YBF_OFF);
    const int ttv = TT * VV;
    for (int u = wid; u < 28; u += 8) {
        const int mt = u / 7, nt = u - mt * 7;
        const int srow = nt * 16 + li;
        const bool sv = srow < SB;
        const int sr = sv ? srow : 0;
        const short8* wb = reinterpret_cast<const short8*>(wpk_s) + (size_t)(mt * 6) * 64 + lane;
        const unsigned short* xb = &xa_s[sr * 192];
        const int sw = (sr & 7) << 3;
        f32x4 y = {0.f,0.f,0.f,0.f};
#pragma unroll
        for (int kap = 0; kap < 6; ++kap) {
            const short8 wf  = wb[(size_t)kap * 64];
            const short8 xaf = *reinterpret_cast<const short8*>(xb + ((kap * 32 + g * 8) ^ sw));
            y = __builtin_amdgcn_mfma_f32_16x16x32_bf16(wf, xaf, y, 0, 0, 0);
        }
        const int oq = mt * 16 + g * 4;
        const size_t base = ((size_t)n * OO + oq) * ttv + (size_t)t0 * VV + srow;
        float vq[4];
        if (BF16Y) {
            unsigned p01 = pk2(y[0], y[1]);
            unsigned p23 = pk2(y[2], y[3]);
            if (sv) {
                ybf[base          ] = (unsigned short)p01;
                ybf[base +     ttv] = (unsigned short)(p01 >> 16);
                ybf[base + 2 * ttv] = (unsigned short)p23;
                ybf[base + 3 * ttv] = (unsigned short)(p23 >> 16);
            }
            // stats on the quantized values (consistent with what bn_relu reads)
            vq[0] = bf2f((unsigned short)p01); vq[1] = bf2f((unsigned short)(p01 >> 16));
            vq[2] = bf2f((unsigned short)p23); vq[3] = bf2f((unsigned short)(p23 >> 16));
        } else {
            if (sv) {
                ypre[base          ] = y[0];
                ypre[base +     ttv] = y[1];
                ypre[base + 2 * ttv] = y[2];
                ypre[base + 3 * ttv] = y[3];
            }
            vq[0] = y[0]; vq[1] = y[1]; vq[2] = y[2]; vq[3] = y[3];
        }
        // within-phase shfl-reduce over the 16 srow lanes (same oq per g-group)
        float s1[4], s2[4];
#pragma unroll
        for (int j = 0; j < 4; ++j) {
            float v = sv ? vq[j] : 0.0f;
            s1[j] = v;
            s2[j] = v * v;
        }
#pragma unroll
        for (int d = 1; d < 16; d <<= 1) {
#pragma unroll
            for (int j = 0; j < 4; ++j) {
                s1[j] += __shfl_xor(s1[j], d);
                s2[j] += __shfl_xor(s2[j], d);
            }
        }
        if (li == 0) {
#pragma unroll
            for (int j = 0; j < 4; ++j) {
                atomicAdd(&stats_s[oq + j], s1[j]);
                atomicAdd(&stats_s[64 + oq + j], s2[j]);
            }
        }
    }
    // NOTE: per-branch bias b.sum(0) is a per-channel constant -> exactly
    // cancelled by training-mode BN. Skipped on purpose (exact).
    __syncthreads();
    if (tid < 128)
        atomicAdd(&ws[REP_OFF + (bid & (NREP - 1)) * 128 + tid], stats_s[tid]);
}

// bn+relu; sums the NREP replica slots inline (16 L2-hot scalar loads).
template <int BF16Y>
__global__ __launch_bounds__(256) void bn_relu(float* __restrict__ out,
                                               const float* __restrict__ ws,
                                               const float* __restrict__ gamma,
                                               const float* __restrict__ beta) {
    const int i4 = blockIdx.x * 256 + threadIdx.x;
    const size_t i = (size_t)i4 * 4;
    const int o = (int)((i / (TT * VV)) % OO);  // TT*VV=7500 divisible by 4

    float sum = 0.0f, sq = 0.0f;
#pragma unroll
    for (int r = 0; r < NREP; ++r) {
        sum += ws[REP_OFF + r * 128 + o];
        sq  += ws[REP_OFF + r * 128 + 64 + o];
    }
    const float cnt  = (float)NN * TT * VV;
    const float mean = sum / cnt;
    const float var  = sq / cnt - mean * mean;
    const float inv  = rsqrtf(var + 1e-5f);
    const float sc   = gamma[o] * inv;
    const float sh   = beta[o] - mean * sc;

    float4 v;
    if (BF16Y) {
        const ushort4 u = *reinterpret_cast<const ushort4*>(
            reinterpret_cast<const unsigned short*>(ws + YBF_OFF) + i);
        v.x = bf2f(u.x); v.y = bf2f(u.y); v.z = bf2f(u.z); v.w = bf2f(u.w);
    } else {
        v = *reinterpret_cast<float4*>(out + i);
    }
    v.x = fmaxf(v.x * sc + sh, 0.0f);
    v.y = fmaxf(v.y * sc + sh, 0.0f);
    v.z = fmaxf(v.z * sc + sh, 0.0f);
    v.w = fmaxf(v.w * sc + sh, 0.0f);
    *reinterpret_cast<float4*>(out + i) = v;
}

extern "C" void kernel_launch(void* const* d_in, const int* in_sizes, int n_in,
                              void* d_out, int out_size, void* d_ws, size_t ws_size,
                              hipStream_t stream) {
    const float* x     = (const float*)d_in[0];
    const float* A     = (const float*)d_in[1];
    const float* W     = (const float*)d_in[2];
    // d_in[3] = b : exactly cancelled by training-mode BN, unused
    const float* gamma = (const float*)d_in[4];
    const float* beta  = (const float*)d_in[5];
    float* out = (float*)d_out;
    float* ws  = (float*)d_ws;

    const bool bf16y = ws_size >= WS_NEED_BF16;  // host-side, deterministic

    hipLaunchKernelGGL(prep_pack, dim3(4), dim3(512), 0, stream, A, W, ws);
    if (bf16y) {
        hipLaunchKernelGGL(HIP_KERNEL_NAME(gcn_main<1>), dim3(NN * (TT / TB)), dim3(512),
                           0, stream, x, ws, out);
        hipLaunchKernelGGL(HIP_KERNEL_NAME(bn_relu<1>), dim3((NN * OO * TT * VV) / 4 / 256),
                           dim3(256), 0, stream, out, ws, gamma, beta);
    } else {
        hipLaunchKernelGGL(HIP_KERNEL_NAME(gcn_main<0>), dim3(NN * (TT / TB)), dim3(512),
                           0, stream, x, ws, out);
        hipLaunchKernelGGL(HIP_KERNEL_NAME(bn_relu<0>), dim3((NN * OO * TT * VV) / 4 / 256),
                           dim3(256), 0, stream, out, ws, gamma, beta);
    }
}

// Round 16
// 68.315 us; speedup vs baseline: 1.2169x; 1.2169x over previous
//
#include <hip/hip_runtime.h>
#include <hip/hip_bf16.h>

// Sizes (fixed by the reference)
#define NN 32
#define CC 64
#define TT 300
#define VV 25
#define KK 3
#define OO 64
#define TB 4          // time steps per block
#define SB (TB * VV)  // 100 output spatial positions per block
#define XROW 28       // x_s row stride; v=25..27 pad ZEROED (bf16 garbage can be
                      // Inf/NaN -> Inf*0=NaN inside MFMA: R15's failure mode)

// ws layout (floats):
//  [0..128)        final stats (sum, sumsq per channel)
//  [128..6272)     Wpk: 1536 short8 W-fragments (24 KB)
//  [6272..7808)    Apk: 384 short8 A-fragments (6 KB)
//  [16384..)       bf16 y buffer (30.72 MB) if ws_size permits
#define WPK_OFF 128
#define APK_OFF (128 + 6144)
#define YBF_OFF 16384
#define YBF_BYTES ((size_t)NN * OO * TT * VV * 2)
#define WS_NEED_BF16 ((size_t)YBF_OFF * 4 + YBF_BYTES)

typedef __attribute__((ext_vector_type(8))) short short8;  // 8 bf16 = 4 VGPR
typedef __attribute__((ext_vector_type(4))) float f32x4;

// f32 -> bf16 RNE, integer path (cold code: prep_pack only)
__device__ __forceinline__ unsigned short f2bf(float f) {
    unsigned u = __builtin_bit_cast(unsigned, f);
    u += 0x7FFFu + ((u >> 16) & 1u);
    return (unsigned short)(u >> 16);
}
__device__ __forceinline__ float bf2f(unsigned short b) {
    return __builtin_bit_cast(float, (unsigned)b << 16);
}
// hot path: official paired convert (RNE, x -> low half); compiler emits the
// packed HW convert (m240: hand-written asm was R13's bug). memcpy not
// bit_cast: __hip_bfloat162 is not trivially copyable on this ROCm.
__device__ __forceinline__ unsigned pk2(float a, float b) {
    __hip_bfloat162 h = __float22bfloat162_rn(make_float2(a, b));
    unsigned r;
    __builtin_memcpy(&r, &h, sizeof(r));
    return r;
}
// 8B-aligned short8 load (x_s rows are 56B-strided -> not 16B-aligned)
__device__ __forceinline__ short8 ld8_b64(const unsigned short* p) {
    uint2 lo = *reinterpret_cast<const uint2*>(p);
    uint2 hi = *reinterpret_cast<const uint2*>(p + 4);
    unsigned tmp[4] = {lo.x, lo.y, hi.x, hi.y};
    short8 r;
    __builtin_memcpy(&r, tmp, 16);
    return r;
}

// One-time: zero stats, pack W and A into exact MFMA fragment layout.
__global__ __launch_bounds__(512) void prep_pack(const float* __restrict__ A,
                                                 const float* __restrict__ W,
                                                 float* __restrict__ ws) {
    const int i = blockIdx.x * 512 + threadIdx.x;  // grid 4 -> 2048 threads
    if (i < 128) ws[i] = 0.0f;
    unsigned short* Wpk = reinterpret_cast<unsigned short*>(ws + WPK_OFF);
    unsigned short* Apk = reinterpret_cast<unsigned short*>(ws + APK_OFF);
    if (i < 1536) {
        // Wpk[mt][kap][lane]: A-operand frag, row o = mt*16+li, k-elems = kap*32+g*8+e
        int mt = i / 384, r = i - mt * 384;
        int kap = r / 64, lane = r - kap * 64;
        int li = lane & 15, g = lane >> 4;
        int o  = mt * 16 + li;
        int k  = kap >> 1, c0 = (kap & 1) * 32 + g * 8;
        const float* wp = W + ((size_t)(k * OO + o)) * CC + c0;
#pragma unroll
        for (int e = 0; e < 8; ++e) Wpk[i * 8 + e] = f2bf(wp[e]);
    } else if (i < 1920) {
        // Apk[k*2+nt][lane]: B-operand frag (A^T), col w = nt*16+li, k-elems v = g*8+e
        // v >= 25 and w >= 25 are ZERO (finite x pad * 0 = 0).
        int j = i - 1536;
        int k = j / 128, r = j - k * 128;
        int nt = r / 64, lane = r - nt * 64;
        int li = lane & 15, g = lane >> 4;
        int w = nt * 16 + li;
#pragma unroll
        for (int e = 0; e < 8; ++e) {
            int v = g * 8 + e;
            float val = (v < VV && w < VV) ? A[(k * VV + v) * VV + w] : 0.0f;
            Apk[j * 8 + e] = f2bf(val);
        }
    }
}

// Block: (n, 4 time steps), 512 threads = 8 waves. R12's 2-barrier schedule,
// LDS diet: 52.8 KB -> 3 blocks/CU (was 79.9 KB -> 2).
//  Phase A: stage x -> bf16 x_s[row=t*64+c][28] (pad v=25..27 zeroed)
//  Phase B: GEMM1 all k -> xa_s[s=t*25+w][kc]   (pk2 uint2 epilogue)
//  Phase C: GEMM2 K=192; W-fragments in 24 VGPR per wave (one mt per wave).
//  NO in-kernel stats (R14 lesson: shfl = LDS-pipe ops, -23us regression).
template <int BF16Y>
__global__ __launch_bounds__(512, 6) void gcn_main(const float* __restrict__ x,
                                                   float* __restrict__ ws,
                                                   float* __restrict__ ypre) {
    __shared__ alignas(16) unsigned short x_s[256 * XROW + 8];  // 14352 B
    __shared__ alignas(16) unsigned short xa_s[100 * 192];      // 38400 B
    // total 52752 B -> 3 blocks/CU

    const int bid  = blockIdx.x;
    const int n    = bid / (TT / TB);
    const int t0   = (bid % (TT / TB)) * TB;
    const int tid  = threadIdx.x;
    const int lane = tid & 63;
    const int wid  = tid >> 6;
    const int li   = lane & 15;   // fragment row/col index
    const int g    = lane >> 4;   // 16-lane group: k-elems = 8g..8g+7

    // ---- Phase C's W-fragments: one mt per wave, 6 coalesced 16B loads -> 24 VGPR.
    const int mtC   = wid >> 1;
    const int halfC = wid & 1;
    short8 wfr[6];
#pragma unroll
    for (int kap = 0; kap < 6; ++kap)
        wfr[kap] = *reinterpret_cast<const short8*>(
            reinterpret_cast<const unsigned short*>(ws + WPK_OFF) +
            ((size_t)(mtC * 6 + kap) * 64 + lane) * 8);

    // ---- A^T B-fragments: 6 coalesced 16B loads (pre-packed)
    short8 afrag[6];
#pragma unroll
    for (int kn = 0; kn < 6; ++kn)
        afrag[kn] = *reinterpret_cast<const short8*>(
            reinterpret_cast<const unsigned short*>(ws + APK_OFF) + ((size_t)kn * 64 + lane) * 8);

    // ---- Phase A: stage x (coalesced float4 global, paired cvt, scalar b16 writes)
    const float* xg = x + (size_t)n * (CC * TT * VV) + (size_t)t0 * VV;
    for (int idx = tid; idx < CC * 25; idx += 512) {  // 1600 float4
        int c = idx / 25, q = idx - c * 25;
        const float4 f = *reinterpret_cast<const float4*>(xg + (size_t)c * (TT * VV) + q * 4);
        unsigned u01 = pk2(f.x, f.y);
        unsigned u23 = pk2(f.z, f.w);
        unsigned short e[4] = {(unsigned short)u01, (unsigned short)(u01 >> 16),
                               (unsigned short)u23, (unsigned short)(u23 >> 16)};
        int s0 = q * 4;
#pragma unroll
        for (int i = 0; i < 4; ++i) {
            int sp = s0 + i;               // may straddle the 25-joint boundary
            int t = sp / 25, v = sp - t * 25;
            x_s[(t * 64 + c) * XROW + v] = e[i];
        }
    }
    // zero the pad: v=25..27 per row + 8-short tail (row 255's g=3 frag reads it).
    // MUST be zero, not garbage: bf16 garbage can decode Inf/NaN and Inf*0=NaN
    // inside MFMA even though afrag is 0 there (R15 failure).
    for (int idx = tid; idx < 256 * 3; idx += 512) {
        int row = idx / 3, v = 25 + (idx - row * 3);
        x_s[row * XROW + v] = 0;
    }
    if (tid < 8) x_s[256 * XROW + tid] = 0;
    __syncthreads();

    // ---- Phase B: GEMM1. M=(t*64+c) 256 rows = 16 Mtiles, N=w (2 tiles), K=32.
    for (int mt = wid; mt < 16; mt += 8) {
        const int row = mt * 16 + li;
        const short8 xf = ld8_b64(&x_s[row * XROW + g * 8]);
        const int r0 = mt * 16 + g * 4;
        const int t = r0 >> 6, c0 = r0 & 63;
        const int s0 = t * 25 + li;
        const int w1 = 16 + li;
        const bool w1v = w1 < VV;
        const int s1 = t * 25 + w1;
        unsigned short* p0 = &xa_s[s0 * 192 + (c0 ^ ((s0 & 7) << 3))];
        unsigned short* p1 = &xa_s[(w1v ? s1 : 0) * 192 + (c0 ^ (((w1v ? s1 : 0) & 7) << 3))];
#pragma unroll
        for (int k = 0; k < KK; ++k) {
            f32x4 a0 = {0.f,0.f,0.f,0.f}, a1 = {0.f,0.f,0.f,0.f};
            a0 = __builtin_amdgcn_mfma_f32_16x16x32_bf16(xf, afrag[k * 2 + 0], a0, 0, 0, 0);
            a1 = __builtin_amdgcn_mfma_f32_16x16x32_bf16(xf, afrag[k * 2 + 1], a1, 0, 0, 0);
            uint2 q0 = make_uint2(pk2(a0[0], a0[1]), pk2(a0[2], a0[3]));
            *reinterpret_cast<uint2*>(p0 + k * 64) = q0;
            if (w1v) {
                uint2 q1 = make_uint2(pk2(a1[0], a1[1]), pk2(a1[2], a1[3]));
                *reinterpret_cast<uint2*>(p1 + k * 64) = q1;
            }
        }
    }
    __syncthreads();

    // ---- Phase C: GEMM2. Wave wid owns mt=wid>>1; nt in {0..3} (half 0) or {4..6}
    // (half 1). K=192 = 6 MFMA from wfr (regs) x xa_s. Invalid srow clamps to row 0
    // (those output columns are store-masked).
    unsigned short* ybf = reinterpret_cast<unsigned short*>(ws + YBF_OFF);
    const int ttv = TT * VV;
    const int nNt = halfC ? 3 : 4;
    const int ntBase = halfC ? 4 : 0;
    for (int qq = 0; qq < nNt; ++qq) {
        const int nt = ntBase + qq;
        const int srow = nt * 16 + li;
        const bool sv = srow < SB;
        const int sr = sv ? srow : 0;
        const unsigned short* xb = &xa_s[sr * 192];
        const int sw = (sr & 7) << 3;
        f32x4 y = {0.f,0.f,0.f,0.f};
#pragma unroll
        for (int kap = 0; kap < 6; ++kap) {
            const short8 xaf = *reinterpret_cast<const short8*>(xb + ((kap * 32 + g * 8) ^ sw));
            y = __builtin_amdgcn_mfma_f32_16x16x32_bf16(wfr[kap], xaf, y, 0, 0, 0);
        }
        const int oq = mtC * 16 + g * 4;
        const size_t base = ((size_t)n * OO + oq) * ttv + (size_t)t0 * VV + srow;
        if (BF16Y) {
            unsigned p01 = pk2(y[0], y[1]);
            unsigned p23 = pk2(y[2], y[3]);
            if (sv) {
                ybf[base          ] = (unsigned short)p01;
                ybf[base +     ttv] = (unsigned short)(p01 >> 16);
                ybf[base + 2 * ttv] = (unsigned short)p23;
                ybf[base + 3 * ttv] = (unsigned short)(p23 >> 16);
            }
        } else {
            if (sv) {
                ypre[base          ] = y[0];
                ypre[base +     ttv] = y[1];
                ypre[base + 2 * ttv] = y[2];
                ypre[base + 3 * ttv] = y[3];
            }
        }
    }
    // NOTE: per-branch bias b.sum(0) is a per-channel constant -> exactly
    // cancelled by training-mode BN. Skipped on purpose (exact).
}

// Per-channel sum/sumsq over y (bandwidth-bound; bf16 variant reads 31 MB).
template <int BF16Y>
__global__ __launch_bounds__(256) void stats_pass(const void* __restrict__ src,
                                                  float* __restrict__ ws) {
    __shared__ float red[8];
    const int b = blockIdx.x;   // n*64 + o
    const int o = b & 63;
    float s1 = 0.0f, s2 = 0.0f;
    if (BF16Y) {
        const ushort4* p = reinterpret_cast<const ushort4*>(
            reinterpret_cast<const unsigned short*>(src) + (size_t)b * (TT * VV));
        for (int i = threadIdx.x; i < (TT * VV) / 4; i += 256) {
            ushort4 u = p[i];
            float a = bf2f(u.x), c = bf2f(u.y), d = bf2f(u.z), e = bf2f(u.w);
            s1 += a + c + d + e;
            s2 += a * a + c * c + d * d + e * e;
        }
    } else {
        const float4* p = reinterpret_cast<const float4*>(
            reinterpret_cast<const float*>(src) + (size_t)b * (TT * VV));
        for (int i = threadIdx.x; i < (TT * VV) / 4; i += 256) {
            float4 v = p[i];
            s1 += v.x + v.y + v.z + v.w;
            s2 += v.x * v.x + v.y * v.y + v.z * v.z + v.w * v.w;
        }
    }
#pragma unroll
    for (int d = 1; d < 64; d <<= 1) {
        s1 += __shfl_xor(s1, d);
        s2 += __shfl_xor(s2, d);
    }
    const int w = threadIdx.x >> 6;
    if ((threadIdx.x & 63) == 0) { red[w] = s1; red[4 + w] = s2; }
    __syncthreads();
    if (threadIdx.x == 0) {
        atomicAdd(&ws[o],      red[0] + red[1] + red[2] + red[3]);
        atomicAdd(&ws[64 + o], red[4] + red[5] + red[6] + red[7]);
    }
}

template <int BF16Y>
__global__ __launch_bounds__(256) void bn_relu(float* __restrict__ out,
                                               const float* __restrict__ ws,
                                               const float* __restrict__ gamma,
                                               const float* __restrict__ beta) {
    const int i4 = blockIdx.x * 256 + threadIdx.x;
    const size_t i = (size_t)i4 * 4;
    const int o = (int)((i / (TT * VV)) % OO);  // TT*VV=7500 divisible by 4

    const float cnt  = (float)NN * TT * VV;
    const float mean = ws[o] / cnt;
    const float var  = ws[OO + o] / cnt - mean * mean;
    const float inv  = rsqrtf(var + 1e-5f);
    const float sc   = gamma[o] * inv;
    const float sh   = beta[o] - mean * sc;

    float4 v;
    if (BF16Y) {
        const ushort4 u = *reinterpret_cast<const ushort4*>(
            reinterpret_cast<const unsigned short*>(ws + YBF_OFF) + i);
        v.x = bf2f(u.x); v.y = bf2f(u.y); v.z = bf2f(u.z); v.w = bf2f(u.w);
    } else {
        v = *reinterpret_cast<float4*>(out + i);
    }
    v.x = fmaxf(v.x * sc + sh, 0.0f);
    v.y = fmaxf(v.y * sc + sh, 0.0f);
    v.z = fmaxf(v.z * sc + sh, 0.0f);
    v.w = fmaxf(v.w * sc + sh, 0.0f);
    *reinterpret_cast<float4*>(out + i) = v;
}

extern "C" void kernel_launch(void* const* d_in, const int* in_sizes, int n_in,
                              void* d_out, int out_size, void* d_ws, size_t ws_size,
                              hipStream_t stream) {
    const float* x     = (const float*)d_in[0];
    const float* A     = (const float*)d_in[1];
    const float* W     = (const float*)d_in[2];
    // d_in[3] = b : exactly cancelled by training-mode BN, unused
    const float* gamma = (const float*)d_in[4];
    const float* beta  = (const float*)d_in[5];
    float* out = (float*)d_out;
    float* ws  = (float*)d_ws;

    const bool bf16y = ws_size >= WS_NEED_BF16;  // host-side, deterministic

    hipLaunchKernelGGL(prep_pack, dim3(4), dim3(512), 0, stream, A, W, ws);
    if (bf16y) {
        hipLaunchKernelGGL(HIP_KERNEL_NAME(gcn_main<1>), dim3(NN * (TT / TB)), dim3(512),
                           0, stream, x, ws, out);
        hipLaunchKernelGGL(HIP_KERNEL_NAME(stats_pass<1>), dim3(NN * OO), dim3(256),
                           0, stream, (const void*)(ws + YBF_OFF), ws);
        hipLaunchKernelGGL(HIP_KERNEL_NAME(bn_relu<1>), dim3((NN * OO * TT * VV) / 4 / 256),
                           dim3(256), 0, stream, out, ws, gamma, beta);
    } else {
        hipLaunchKernelGGL(HIP_KERNEL_NAME(gcn_main<0>), dim3(NN * (TT / TB)), dim3(512),
                           0, stream, x, ws, out);
        hipLaunchKernelGGL(HIP_KERNEL_NAME(stats_pass<0>), dim3(NN * OO), dim3(256),
                           0, stream, (const void*)out, ws);
        hipLaunchKernelGGL(HIP_KERNEL_NAME(bn_relu<0>), dim3((NN * OO * TT * VV) / 4 / 256),
                           dim3(256), 0, stream, out, ws, gamma, beta);
    }
}

// Round 17
// 57.398 us; speedup vs baseline: 1.4483x; 1.1902x over previous
//
#include <hip/hip_runtime.h>
#include <hip/hip_bf16.h>

// Sizes (fixed by the reference)
#define NN 32
#define CC 64
#define TT 300
#define VV 25
#define KK 3
#define OO 64
#define TB 4          // time steps per block
#define SB (TB * VV)  // 100 output spatial positions per block
#define NREP 8        // replicated stats accumulator slots

// ws layout (floats):
//  [0..1024)       NREP*128 replica stats accumulators (sum, sumsq per channel)
//  [1024..7168)    Wpk: 1536 short8 W-fragments (24 KB)
//  [7168..8704)    Apk: 384 short8 A-fragments (6 KB)
//  [16384..)       bf16 y buffer (30.72 MB) if ws_size permits
#define REP_OFF 0
#define WPK_OFF 1024
#define APK_OFF 7168
#define YBF_OFF 16384
#define YBF_BYTES ((size_t)NN * OO * TT * VV * 2)
#define WS_NEED_BF16 ((size_t)YBF_OFF * 4 + YBF_BYTES)

typedef __attribute__((ext_vector_type(8))) short short8;  // 8 bf16 = 4 VGPR
typedef __attribute__((ext_vector_type(4))) float f32x4;

// f32 -> bf16 RNE, integer path (cold code: prep_pack only)
__device__ __forceinline__ unsigned short f2bf(float f) {
    unsigned u = __builtin_bit_cast(unsigned, f);
    u += 0x7FFFu + ((u >> 16) & 1u);
    return (unsigned short)(u >> 16);
}
__device__ __forceinline__ float bf2f(unsigned short b) {
    return __builtin_bit_cast(float, (unsigned)b << 16);
}
// hot path: official paired convert (RNE, x -> low half); compiler emits the
// packed HW convert (m240: hand-written asm was R13's bug). memcpy not
// bit_cast: __hip_bfloat162 is not trivially copyable on this ROCm.
__device__ __forceinline__ unsigned pk2(float a, float b) {
    __hip_bfloat162 h = __float22bfloat162_rn(make_float2(a, b));
    unsigned r;
    __builtin_memcpy(&r, &h, sizeof(r));
    return r;
}

// One-time: zero replica stats, pack W and A into exact MFMA fragment layout.
__global__ __launch_bounds__(512) void prep_pack(const float* __restrict__ A,
                                                 const float* __restrict__ W,
                                                 float* __restrict__ ws) {
    const int i = blockIdx.x * 512 + threadIdx.x;  // grid 4 -> 2048 threads
    if (i < NREP * 128) ws[REP_OFF + i] = 0.0f;
    unsigned short* Wpk = reinterpret_cast<unsigned short*>(ws + WPK_OFF);
    unsigned short* Apk = reinterpret_cast<unsigned short*>(ws + APK_OFF);
    if (i < 1536) {
        // Wpk[mt][kap][lane]: A-operand frag, row o = mt*16+li, k-elems = kap*32+g*8+e
        int mt = i / 384, r = i - mt * 384;
        int kap = r / 64, lane = r - kap * 64;
        int li = lane & 15, g = lane >> 4;
        int o  = mt * 16 + li;
        int k  = kap >> 1, c0 = (kap & 1) * 32 + g * 8;
        const float* wp = W + ((size_t)(k * OO + o)) * CC + c0;
#pragma unroll
        for (int e = 0; e < 8; ++e) Wpk[i * 8 + e] = f2bf(wp[e]);
    } else if (i < 1920) {
        // Apk[k*2+nt][lane]: B-operand frag (A^T), col w = nt*16+li, k-elems v = g*8+e
        // v >= 25 and w >= 25 are ZERO (finite x values * 0 = 0; x side must be
        // finite, never uninitialized-LDS garbage -> R15's NaN failure).
        int j = i - 1536;
        int k = j / 128, r = j - k * 128;
        int nt = r / 64, lane = r - nt * 64;
        int li = lane & 15, g = lane >> 4;
        int w = nt * 16 + li;
#pragma unroll
        for (int e = 0; e < 8; ++e) {
            int v = g * 8 + e;
            float val = (v < VV && w < VV) ? A[(k * VV + v) * VV + w] : 0.0f;
            Apk[j * 8 + e] = f2bf(val);
        }
    }
}

// Block: (n, 4 time steps), 512 threads = 8 waves.
//  x fragments loaded DIRECTLY from global per lane (Phase A / x_s / 1st barrier
//  eliminated: B's operand is lane-local, no cross-lane redistribution needed).
//  Phase B: GEMM1 all k -> xa_s[s=t*25+w][kc]   (pk2 uint2 epilogue)
//  barrier
//  Phase C: GEMM2 K=192, wfr in 24 VGPR (one mt per wave) -> stores + reg-stats
//  Stats: 8-reg accumulate (oq constant per thread), ONE shfl-tree at kernel end
//  (R14 lesson: per-iter shfl = LDS-pipe flood; once-per-kernel is ~3% of that).
template <int BF16Y>
__global__ __launch_bounds__(512, 6) void gcn_main(const float* __restrict__ x,
                                                   float* __restrict__ ws,
                                                   float* __restrict__ ypre) {
    __shared__ alignas(16) unsigned short xa_s[100 * 192];  // 38400 B (only LDS)
    __shared__ float stats_s[128];

    const int bid  = blockIdx.x;
    const int n    = bid / (TT / TB);
    const int t0   = (bid % (TT / TB)) * TB;
    const int tid  = threadIdx.x;
    const int lane = tid & 63;
    const int wid  = tid >> 6;
    const int li   = lane & 15;   // fragment row/col index
    const int g    = lane >> 4;   // 16-lane group: k-elems = 8g..8g+7

    if (tid < 128) stats_s[tid] = 0.0f;

    // ---- x fragments straight from global: lane (li,g) owns rows (wid+8m)*16+li,
    // elems v = 8g..8g+7 (g=3: only v=24 valid; rest zeroed in-register, finite).
    const float* xn = x + (size_t)n * (CC * TT * VV);
    short8 xf[2];
#pragma unroll
    for (int m = 0; m < 2; ++m) {
        const int row = (wid + 8 * m) * 16 + li;
        const int c = row & 63, t = row >> 6;
        const float* xr = xn + (size_t)c * (TT * VV) + (size_t)(t0 + t) * VV + g * 8;
        float e0, e1, e2, e3, e4, e5, e6, e7;
        if (g < 3) {
            e0 = xr[0]; e1 = xr[1]; e2 = xr[2]; e3 = xr[3];
            e4 = xr[4]; e5 = xr[5]; e6 = xr[6]; e7 = xr[7];
        } else {
            e0 = xr[0];  // v = 24
            e1 = e2 = e3 = e4 = e5 = e6 = e7 = 0.0f;
        }
        unsigned p[4] = {pk2(e0, e1), pk2(e2, e3), pk2(e4, e5), pk2(e6, e7)};
        __builtin_memcpy(&xf[m], p, 16);
    }

    // ---- A^T B-fragments: 6 coalesced 16B loads (pre-packed, L2-hot)
    short8 afrag[6];
#pragma unroll
    for (int kn = 0; kn < 6; ++kn)
        afrag[kn] = *reinterpret_cast<const short8*>(
            reinterpret_cast<const unsigned short*>(ws + APK_OFF) + ((size_t)kn * 64 + lane) * 8);

    // ---- Phase B: GEMM1 (no pre-barrier: xf is lane-local).
    // M=(t*64+c) 256 rows = 16 Mtiles (2/wave), N=w (2 tiles), K=32.
#pragma unroll
    for (int m = 0; m < 2; ++m) {
        const int mt = wid + 8 * m;
        const int r0 = mt * 16 + g * 4;
        const int tq = r0 >> 6, c0 = r0 & 63;
        const int sa = tq * 25 + li;
        const int w1 = 16 + li;
        const bool w1v = w1 < VV;
        const int sb = tq * 25 + w1;
        unsigned short* p0 = &xa_s[sa * 192 + (c0 ^ ((sa & 7) << 3))];
        unsigned short* p1 = &xa_s[(w1v ? sb : 0) * 192 + (c0 ^ (((w1v ? sb : 0) & 7) << 3))];
#pragma unroll
        for (int k = 0; k < KK; ++k) {
            f32x4 a0 = {0.f,0.f,0.f,0.f}, a1 = {0.f,0.f,0.f,0.f};
            a0 = __builtin_amdgcn_mfma_f32_16x16x32_bf16(xf[m], afrag[k * 2 + 0], a0, 0, 0, 0);
            a1 = __builtin_amdgcn_mfma_f32_16x16x32_bf16(xf[m], afrag[k * 2 + 1], a1, 0, 0, 0);
            uint2 q0 = make_uint2(pk2(a0[0], a0[1]), pk2(a0[2], a0[3]));
            *reinterpret_cast<uint2*>(p0 + k * 64) = q0;
            if (w1v) {
                uint2 q1 = make_uint2(pk2(a1[0], a1[1]), pk2(a1[2], a1[3]));
                *reinterpret_cast<uint2*>(p1 + k * 64) = q1;
            }
        }
    }
    __syncthreads();

    // ---- Phase C's W-fragments: loaded AFTER the barrier (frees regs during B).
    const int mtC   = wid >> 1;
    const int halfC = wid & 1;
    short8 wfr[6];
#pragma unroll
    for (int kap = 0; kap < 6; ++kap)
        wfr[kap] = *reinterpret_cast<const short8*>(
            reinterpret_cast<const unsigned short*>(ws + WPK_OFF) +
            ((size_t)(mtC * 6 + kap) * 64 + lane) * 8);

    // ---- Phase C: GEMM2. Wave wid owns mt=wid>>1; nt in {0..3} / {4..6}.
    // K=192 = 6 MFMA from wfr (regs) x xa_s. Invalid srow clamps to row 0.
    unsigned short* ybf = reinterpret_cast<unsigned short*>(ws + YBF_OFF);
    const int ttv = TT * VV;
    const int oq  = mtC * 16 + g * 4;   // constant per thread across nt loop
    const int nNt = halfC ? 3 : 4;
    const int ntBase = halfC ? 4 : 0;
    float s1[4] = {0.f,0.f,0.f,0.f}, s2[4] = {0.f,0.f,0.f,0.f};
    for (int qq = 0; qq < nNt; ++qq) {
        const int nt = ntBase + qq;
        const int srow = nt * 16 + li;
        const bool sv = srow < SB;
        const int sr = sv ? srow : 0;
        const unsigned short* xb = &xa_s[sr * 192];
        const int sw = (sr & 7) << 3;
        f32x4 y = {0.f,0.f,0.f,0.f};
#pragma unroll
        for (int kap = 0; kap < 6; ++kap) {
            const short8 xaf = *reinterpret_cast<const short8*>(xb + ((kap * 32 + g * 8) ^ sw));
            y = __builtin_amdgcn_mfma_f32_16x16x32_bf16(wfr[kap], xaf, y, 0, 0, 0);
        }
        const size_t base = ((size_t)n * OO + oq) * ttv + (size_t)t0 * VV + srow;
        float vq[4];
        if (BF16Y) {
            unsigned p01 = pk2(y[0], y[1]);
            unsigned p23 = pk2(y[2], y[3]);
            if (sv) {
                ybf[base          ] = (unsigned short)p01;
                ybf[base +     ttv] = (unsigned short)(p01 >> 16);
                ybf[base + 2 * ttv] = (unsigned short)p23;
                ybf[base + 3 * ttv] = (unsigned short)(p23 >> 16);
            }
            // stats on quantized values (consistent with what bn_relu reads)
            vq[0] = bf2f((unsigned short)p01); vq[1] = bf2f((unsigned short)(p01 >> 16));
            vq[2] = bf2f((unsigned short)p23); vq[3] = bf2f((unsigned short)(p23 >> 16));
        } else {
            if (sv) {
                ypre[base          ] = y[0];
                ypre[base +     ttv] = y[1];
                ypre[base + 2 * ttv] = y[2];
                ypre[base + 3 * ttv] = y[3];
            }
            vq[0] = y[0]; vq[1] = y[1]; vq[2] = y[2]; vq[3] = y[3];
        }
#pragma unroll
        for (int j = 0; j < 4; ++j) {
            float v = sv ? vq[j] : 0.0f;
            s1[j] += v;
            s2[j] += v * v;
        }
    }
    // ---- ONE reduction at kernel end: 4-step shfl over li, LDS atomics, then
    // 128 replicated global atomics. (vs R14's per-iter shfl: ~3% of the LDS ops)
#pragma unroll
    for (int d = 1; d < 16; d <<= 1) {
#pragma unroll
        for (int j = 0; j < 4; ++j) {
            s1[j] += __shfl_xor(s1[j], d);
            s2[j] += __shfl_xor(s2[j], d);
        }
    }
    if (li == 0) {
#pragma unroll
        for (int j = 0; j < 4; ++j) {
            atomicAdd(&stats_s[oq + j], s1[j]);
            atomicAdd(&stats_s[64 + oq + j], s2[j]);
        }
    }
    // NOTE: per-branch bias b.sum(0) is a per-channel constant -> exactly
    // cancelled by training-mode BN. Skipped on purpose (exact).
    __syncthreads();
    if (tid < 128)
        atomicAdd(&ws[REP_OFF + (bid & (NREP - 1)) * 128 + tid], stats_s[tid]);
}

// bn+relu; folds the NREP replica slots inline (wave-uniform, L1-broadcast).
template <int BF16Y>
__global__ __launch_bounds__(256) void bn_relu(float* __restrict__ out,
                                               const float* __restrict__ ws,
                                               const float* __restrict__ gamma,
                                               const float* __restrict__ beta) {
    const int i4 = blockIdx.x * 256 + threadIdx.x;
    const size_t i = (size_t)i4 * 4;
    const int o = (int)((i / (TT * VV)) % OO);  // TT*VV=7500 divisible by 4

    float sum = 0.0f, sq = 0.0f;
#pragma unroll
    for (int r = 0; r < NREP; ++r) {
        sum += ws[REP_OFF + r * 128 + o];
        sq  += ws[REP_OFF + r * 128 + 64 + o];
    }
    const float cnt  = (float)NN * TT * VV;
    const float mean = sum / cnt;
    const float var  = sq / cnt - mean * mean;
    const float inv  = rsqrtf(var + 1e-5f);
    const float sc   = gamma[o] * inv;
    const float sh   = beta[o] - mean * sc;

    float4 v;
    if (BF16Y) {
        const ushort4 u = *reinterpret_cast<const ushort4*>(
            reinterpret_cast<const unsigned short*>(ws + YBF_OFF) + i);
        v.x = bf2f(u.x); v.y = bf2f(u.y); v.z = bf2f(u.z); v.w = bf2f(u.w);
    } else {
        v = *reinterpret_cast<float4*>(out + i);
    }
    v.x = fmaxf(v.x * sc + sh, 0.0f);
    v.y = fmaxf(v.y * sc + sh, 0.0f);
    v.z = fmaxf(v.z * sc + sh, 0.0f);
    v.w = fmaxf(v.w * sc + sh, 0.0f);
    *reinterpret_cast<float4*>(out + i) = v;
}

extern "C" void kernel_launch(void* const* d_in, const int* in_sizes, int n_in,
                              void* d_out, int out_size, void* d_ws, size_t ws_size,
                              hipStream_t stream) {
    const float* x     = (const float*)d_in[0];
    const float* A     = (const float*)d_in[1];
    const float* W     = (const float*)d_in[2];
    // d_in[3] = b : exactly cancelled by training-mode BN, unused
    const float* gamma = (const float*)d_in[4];
    const float* beta  = (const float*)d_in[5];
    float* out = (float*)d_out;
    float* ws  = (float*)d_ws;

    const bool bf16y = ws_size >= WS_NEED_BF16;  // host-side, deterministic

    hipLaunchKernelGGL(prep_pack, dim3(4), dim3(512), 0, stream, A, W, ws);
    if (bf16y) {
        hipLaunchKernelGGL(HIP_KERNEL_NAME(gcn_main<1>), dim3(NN * (TT / TB)), dim3(512),
                           0, stream, x, ws, out);
        hipLaunchKernelGGL(HIP_KERNEL_NAME(bn_relu<1>), dim3((NN * OO * TT * VV) / 4 / 256),
                           dim3(256), 0, stream, out, ws, gamma, beta);
    } else {
        hipLaunchKernelGGL(HIP_KERNEL_NAME(gcn_main<0>), dim3(NN * (TT / TB)), dim3(512),
                           0, stream, x, ws, out);
        hipLaunchKernelGGL(HIP_KERNEL_NAME(bn_relu<0>), dim3((NN * OO * TT * VV) / 4 / 256),
                           dim3(256), 0, stream, out, ws, gamma, beta);
    }
}